// Round 2
// baseline (613.058 us; speedup 1.0000x reference)
//
#include <hip/hip_runtime.h>

#define NBLK_EDGE 768          // blocks for hist/reorder; chunking must match between them
#define CHUNKE 10432           // max edges per reorder block (75KB LDS -> 2 blocks/CU)
#define BIN_SHIFT 10
#define BIN_SIZE 1024          // nodes per bin
#define MAXK 1024              // scan width; K = ceil(N/1024) = 489 for N=500K
#define ROW_BITS 19            // N=500,000 < 2^19
#define ROW_MASK ((1u << ROW_BITS) - 1)

typedef _Float16 half8  __attribute__((ext_vector_type(8)));
typedef _Float16 half2v __attribute__((ext_vector_type(2)));

// ---- shfl-based scans ------------------------------------------------------
__device__ __forceinline__ int wave_scan_incl(int v, int lane) {
#pragma unroll
    for (int d = 1; d < 64; d <<= 1) {
        int u = __shfl_up(v, d, 64);
        if (lane >= d) v += u;
    }
    return v;
}

// block-wide exclusive scan over 1024 per-thread values; wsum = __shared__ int[16]
__device__ __forceinline__ int block_excl_scan_1024(int v, int tid, int* wsum) {
    int lane = tid & 63, wv = tid >> 6;
    int incl = wave_scan_incl(v, lane);
    if (lane == 63) wsum[wv] = incl;
    __syncthreads();
    if (tid < 16) {
        int w = wsum[tid];
#pragma unroll
        for (int d = 1; d < 16; d <<= 1) {
            int u = __shfl_up(w, d, 16);
            if (tid >= d) w += u;
        }
        wsum[tid] = w;
    }
    __syncthreads();
    return incl - v + (wv ? wsum[wv - 1] : 0);
}

// Per-block LDS histogram of col>>BIN_SHIFT; persists per-block rows in both
// layouts: cntB (block-major, reload in k_reorder) and cntT (bin-major).
__global__ void __launch_bounds__(1024) k_hist(
        const int* __restrict__ col, int E, int chunk, int K,
        int* __restrict__ cntB, int* __restrict__ cntT) {
    __shared__ int lh[MAXK];
    int blk = blockIdx.x;
    for (int k = threadIdx.x; k < MAXK; k += blockDim.x) lh[k] = 0;
    __syncthreads();
    int s = blk * chunk, e_ = min(s + chunk, E);
    for (int e = s + threadIdx.x; e < e_; e += blockDim.x)
        atomicAdd(&lh[col[e] >> BIN_SHIFT], 1);
    __syncthreads();
    for (int k = threadIdx.x; k < MAXK; k += blockDim.x) {
        int v = lh[k];
        cntB[(size_t)blk * MAXK + k] = v;
        cntT[(size_t)k * NBLK_EDGE + blk] = v;
    }
}

// Per-bin exclusive scan over the NBLK_EDGE per-block counts (in-place) and
// per-bin total -> ghist. One block per bin, 3 elements/thread (768 = 256*3).
__global__ void k_colscan(int* __restrict__ cntT, int* __restrict__ ghist) {
    __shared__ int part[256];
    int b = blockIdx.x, tid = threadIdx.x;
    size_t base = (size_t)b * NBLK_EDGE;
    int t3 = tid * 3;
    int c0 = cntT[base + t3], c1 = cntT[base + t3 + 1], c2 = cntT[base + t3 + 2];
    int sum = c0 + c1 + c2;
    part[tid] = sum;
    __syncthreads();
    for (int off = 1; off < 256; off <<= 1) {
        int v = (tid >= off) ? part[tid - off] : 0;
        __syncthreads();
        part[tid] += v;
        __syncthreads();
    }
    int excl = part[tid] - sum;
    cntT[base + t3]     = excl;
    cntT[base + t3 + 1] = excl + c0;
    cntT[base + t3 + 2] = excl + c0 + c1;
    if (tid == 255) ghist[b] = part[255];  // bin total
}

// Exclusive scan over K<=MAXK bins (single block of MAXK threads).
__global__ void k_scan(const int* __restrict__ ghist, int K, int* __restrict__ binBase) {
    __shared__ int wsum[16];
    int tid = threadIdx.x;
    int val = (tid < K) ? ghist[tid] : 0;
    int excl = block_excl_scan_1024(val, tid, wsum);
    if (tid < K) binBase[tid] = excl;
    if (tid == K - 1) binBase[K] = excl + val;  // == E
}

// Reorder with LOCAL SORT: place the block's chunk bin-sorted in LDS, then
// write out in contiguous per-bin runs (~21 edges = 85B, near-full lines).
// 75KB LDS -> 2 blocks/CU -> 32 waves/CU.
__global__ void __launch_bounds__(1024) k_reorder(
        const int* __restrict__ row, const int* __restrict__ col,
        int E, int chunk, int K,
        const int* __restrict__ binBase, const int* __restrict__ cntB,
        const int* __restrict__ cntT, unsigned* __restrict__ packed) {
    __shared__ unsigned sorted[CHUNKE];       // 40.75 KB
    __shared__ unsigned short sbin[CHUNKE];   // 20.4 KB
    __shared__ int lcur[MAXK], lbase[MAXK], gbase[MAXK];  // 12 KB
    __shared__ int wsum[16];
    int blk = blockIdx.x, tid = threadIdx.x;
    int s = blk * chunk, e_ = min(s + chunk, E), len = e_ - s;
    size_t bb = (size_t)blk * MAXK;
    int c0 = cntB[bb + tid];
    int excl = block_excl_scan_1024(c0, tid, wsum);
    lbase[tid] = excl;
    lcur[tid] = excl;
    gbase[tid] = binBase[tid] + cntT[(size_t)tid * NBLK_EDGE + blk];
    __syncthreads();
    // placement: bin-sorted staging in LDS (1 LDS atomic per edge)
    for (int i = tid; i < len; i += blockDim.x) {
        int cc = col[s + i];
        int b = cc >> BIN_SHIFT;
        int slot = atomicAdd(&lcur[b], 1);
        sorted[slot] = ((unsigned)(cc & (BIN_SIZE - 1)) << ROW_BITS) | (unsigned)row[s + i];
        sbin[slot] = (unsigned short)b;
    }
    __syncthreads();
    // coalesced run write-out
    for (int i = tid; i < len; i += blockDim.x) {
        int b = sbin[i];
        packed[gbase[b] + (i - lbase[b])] = sorted[i];
    }
}

// Per-bin degree count (1 LDS int atomic/edge) -> dinv, fused with the
// layer-1 MLP: g0 = f16(dinv * (x @ W1)). Replaces the whole binsort.
__global__ void __launch_bounds__(1024) k_degmlp(
        const unsigned* __restrict__ packed, const int* __restrict__ binBase,
        const float* __restrict__ x, const float* __restrict__ W1,
        float* __restrict__ dinv, half8* __restrict__ g0, int N) {
    __shared__ int cnt[BIN_SIZE];
    __shared__ float w1s[128];
    int tid = threadIdx.x, bin = blockIdx.x;
    cnt[tid] = 0;
    if (tid < 128) w1s[tid] = W1[tid];
    __syncthreads();
    int s = binBase[bin], t = binBase[bin + 1];
    for (int i = s + tid; i < t; i += 1024)
        atomicAdd(&cnt[packed[i] >> ROW_BITS], 1);
    __syncthreads();
    int node = (bin << BIN_SHIFT) + tid;
    if (node < N) {
        float di = rsqrtf((float)(cnt[tid] + 1));  // +1 self-loop
        dinv[node] = di;
        const float4* xv = (const float4*)(x + (size_t)node * 16);
        float h[8];
#pragma unroll
        for (int j = 0; j < 8; ++j) h[j] = 0.0f;
#pragma unroll
        for (int kk = 0; kk < 4; ++kk) {
            float4 a = xv[kk];
            int kb = kk * 4;
#pragma unroll
            for (int j = 0; j < 8; ++j)
                h[j] += a.x * w1s[kb * 8 + j] + a.y * w1s[(kb + 1) * 8 + j]
                      + a.z * w1s[(kb + 2) * 8 + j] + a.w * w1s[(kb + 3) * 8 + j];
        }
        half8 g;
#pragma unroll
        for (int j = 0; j < 8; ++j) g[j] = (_Float16)(di * h[j]);
        g0[node] = g;
    }
}

// Layer-1 gather, EDGE-PARALLEL per bin: coalesced packed reads, LDS f32
// atomic accumulation into acc[j][node] ([j][node] layout -> bank = node%32,
// conflict-free for random dests). Tail: h = relu(di*(acc+self)+b1), g1.
__global__ void __launch_bounds__(1024) k_g1(
        const unsigned* __restrict__ packed, const int* __restrict__ binBase,
        const half8* __restrict__ g0, const float* __restrict__ dinv,
        const float* __restrict__ b1, const float* __restrict__ W2,
        half2v* __restrict__ g1, int N) {
    __shared__ float acc[8][BIN_SIZE];   // 32 KB
    int tid = threadIdx.x, bin = blockIdx.x;
#pragma unroll
    for (int j = 0; j < 8; ++j) acc[j][tid] = 0.0f;
    __syncthreads();
    int s = binBase[bin], t = binBase[bin + 1];
    for (int i = s + tid; i < t; i += 1024) {
        unsigned v = packed[i];
        int d = (int)(v >> ROW_BITS);
        half8 sv = g0[v & ROW_MASK];
#pragma unroll
        for (int j = 0; j < 8; ++j) atomicAdd(&acc[j][d], (float)sv[j]);
    }
    __syncthreads();
    int node = (bin << BIN_SHIFT) + tid;
    if (node < N) {
        float di = dinv[node];
        half8 self = g0[node];
        float o0 = 0.0f, o1 = 0.0f;
#pragma unroll
        for (int j = 0; j < 8; ++j) {
            float hj = fmaxf(di * (acc[j][tid] + (float)self[j]) + b1[j], 0.0f);
            o0 += hj * W2[j * 2 + 0];
            o1 += hj * W2[j * 2 + 1];
        }
        half2v g;
        g.x = (_Float16)(di * o0);
        g.y = (_Float16)(di * o1);
        g1[node] = g;
    }
}

// Layer-2 gather, edge-parallel per bin (g1 = 2MB, L2-resident), fused with
// log-softmax epilogue. Coalesced float2 out writes per bin.
__global__ void __launch_bounds__(1024) k_g2(
        const unsigned* __restrict__ packed, const int* __restrict__ binBase,
        const half2v* __restrict__ g1, const float* __restrict__ dinv,
        const float* __restrict__ b2, float* __restrict__ out, int N) {
    __shared__ float acc0[BIN_SIZE], acc1[BIN_SIZE];   // 8 KB
    int tid = threadIdx.x, bin = blockIdx.x;
    acc0[tid] = 0.0f;
    acc1[tid] = 0.0f;
    __syncthreads();
    int s = binBase[bin], t = binBase[bin + 1];
    for (int i = s + tid; i < t; i += 1024) {
        unsigned v = packed[i];
        int d = (int)(v >> ROW_BITS);
        half2v sv = g1[v & ROW_MASK];
        atomicAdd(&acc0[d], (float)sv.x);
        atomicAdd(&acc1[d], (float)sv.y);
    }
    __syncthreads();
    int node = (bin << BIN_SHIFT) + tid;
    if (node < N) {
        float di = dinv[node];
        half2v self = g1[node];
        float o0 = di * (acc0[tid] + (float)self.x) + b2[0];
        float o1 = di * (acc1[tid] + (float)self.y) + b2[1];
        float m = fmaxf(o0, o1);
        float lse = m + logf(expf(o0 - m) + expf(o1 - m));
        ((float2*)out)[node] = make_float2(o0 - lse, o1 - lse);
    }
}

extern "C" void kernel_launch(void* const* d_in, const int* in_sizes, int n_in,
                              void* d_out, int out_size, void* d_ws, size_t ws_size,
                              hipStream_t stream) {
    const float* x  = (const float*)d_in[0];
    const float* W1 = (const float*)d_in[1];
    const float* b1 = (const float*)d_in[2];
    const float* W2 = (const float*)d_in[3];
    const float* b2 = (const float*)d_in[4];
    const int*   ei = (const int*)d_in[5];

    const int N = in_sizes[0] / 16;
    const int E = in_sizes[5] / 2;
    const int* row = ei;
    const int* col = ei + E;
    const int K = (N + BIN_SIZE - 1) >> BIN_SHIFT;  // 489 for N=500K

    float* ws   = (float*)d_ws;
    float* dinv = ws;                              // N floats
    half8* g0   = (half8*)(ws + (size_t)N);        // 4N floats worth
    half2v* g1  = (half2v*)(ws + (size_t)5 * N);   // N floats worth
    int*   meta = (int*)(ws + (size_t)6 * N);
    int* ghist      = meta;                        // MAXK ints
    int* binBase    = meta + MAXK;                 // MAXK+1 ints (padded)
    unsigned* packed = (unsigned*)(meta + 3 * MAXK);          // E uints
    int* cntB = (int*)(packed + E);                // MAXK*NBLK_EDGE ints
    int* cntT = cntB + (size_t)MAXK * NBLK_EDGE;   // MAXK*NBLK_EDGE ints

    float* out = (float*)d_out;

    const int chunk = (E + NBLK_EDGE - 1) / NBLK_EDGE;  // 10417 <= CHUNKE

    k_hist   <<<NBLK_EDGE, 1024, 0, stream>>>(col, E, chunk, K, cntB, cntT);
    k_colscan<<<K, 256, 0, stream>>>(cntT, ghist);
    k_scan   <<<1, MAXK, 0, stream>>>(ghist, K, binBase);
    k_reorder<<<NBLK_EDGE, 1024, 0, stream>>>(row, col, E, chunk, K,
                                              binBase, cntB, cntT, packed);
    k_degmlp <<<K, 1024, 0, stream>>>(packed, binBase, x, W1, dinv, g0, N);
    k_g1     <<<K, 1024, 0, stream>>>(packed, binBase, g0, dinv, b1, W2, g1, N);
    k_g2     <<<K, 1024, 0, stream>>>(packed, binBase, g1, dinv, b2, out, N);
}